// Round 1
// baseline (5112.815 us; speedup 1.0000x reference)
//
#include <hip/hip_runtime.h>
#include <math.h>

#define F 64
#define VIOL_THRESH 0.2f

__global__ void init_kernel(int* __restrict__ min1, int* __restrict__ min2,
                            float* __restrict__ accf, int* __restrict__ acci, int n) {
    int i = blockIdx.x * blockDim.x + threadIdx.x;
    if (i < n) { min1[i] = n; min2[i] = n; }
    if (i == 0) { accf[0] = 0.f; accf[1] = 0.f; acci[0] = 0; }
}

__global__ void edge_min1_kernel(const int* __restrict__ e0, const int* __restrict__ e1,
                                 int* __restrict__ min1, int m) {
    int j = blockIdx.x * blockDim.x + threadIdx.x;
    if (j >= m) return;
    int u = e0[j], v = e1[j];
    if (u != v) {
        atomicMin(&min1[u], v);
        atomicMin(&min1[v], u);
    }
}

__global__ void edge_min2_kernel(const int* __restrict__ e0, const int* __restrict__ e1,
                                 const int* __restrict__ min1, int* __restrict__ min2, int m) {
    int j = blockIdx.x * blockDim.x + threadIdx.x;
    if (j >= m) return;
    int u = e0[j], v = e1[j];
    if (u != v) {
        if (v != min1[u]) atomicMin(&min2[u], v);
        if (u != min1[v]) atomicMin(&min2[v], u);
    }
}

__global__ __launch_bounds__(256)
void node_kernel(const float* __restrict__ feat, const float* __restrict__ radii,
                 const float* __restrict__ w1rc, const float* __restrict__ b1rc,
                 const float* __restrict__ w2rc, const float* __restrict__ b2rc,
                 const float* __restrict__ w3rc, const float* __restrict__ b3rc,
                 const float* __restrict__ w1cp, const float* __restrict__ b1cp,
                 const float* __restrict__ w2cp, const float* __restrict__ b2cp,
                 const int* __restrict__ types,
                 const int* __restrict__ min1, const int* __restrict__ min2,
                 float* __restrict__ out, float* __restrict__ accf, int* __restrict__ acci,
                 int n) {
    int i = blockIdx.x * blockDim.x + threadIdx.x;
    bool live = i < n;
    int ii = live ? i : (n - 1);

    int m1 = min1[ii];
    int m2 = min2[ii];
    bool valid = m2 < n;
    int c1 = m1 < n ? m1 : (n - 1);   // m1 >= 0 always (node ids)
    int c2 = m2 < n ? m2 : (n - 1);

    // ---- layer-1 of both MLPs: combined[192] @ (w1rc | w1cp) ----
    float hrc[F], hcp[F];
#pragma unroll
    for (int o = 0; o < F; o++) { hrc[o] = b1rc[o]; hcp[o] = b1cp[o]; }

    for (int part = 0; part < 3; part++) {
        int row = (part == 0) ? ii : ((part == 1) ? c1 : c2);
        const float4* rp = (const float4*)(feat + (size_t)row * F);
        float c[F];
#pragma unroll
        for (int q = 0; q < F / 4; q++) {
            float4 v = rp[q];
            c[q * 4 + 0] = v.x; c[q * 4 + 1] = v.y;
            c[q * 4 + 2] = v.z; c[q * 4 + 3] = v.w;
        }
        const float* wr = w1rc + (size_t)part * F * F;   // [k][o], k local to part
        const float* wc = w1cp + (size_t)part * F * F;
#pragma unroll
        for (int o = 0; o < F; o++) {
            float s1 = 0.f, s2 = 0.f;
#pragma unroll
            for (int kk = 0; kk < F; kk++) {
                s1 = fmaf(c[kk], wr[kk * F + o], s1);
                s2 = fmaf(c[kk], wc[kk * F + o], s2);
            }
            hrc[o] += s1;
            hcp[o] += s2;
        }
    }
#pragma unroll
    for (int o = 0; o < F; o++) {
        hrc[o] = fmaxf(hrc[o], 0.f);
        hcp[o] = fmaxf(hcp[o], 0.f);
    }

    // ---- rc layer-2 (64->32, relu) fused with layer-3 (32->1) ----
    float corr = b3rc[0];
#pragma unroll
    for (int o = 0; o < 32; o++) {
        float s = b2rc[o];
#pragma unroll
        for (int k = 0; k < F; k++) s = fmaf(hrc[k], w2rc[k * 32 + o], s);
        s = fmaxf(s, 0.f);
        corr = fmaf(s, w3rc[o], corr);
    }

    // ---- cp output (64->1, sigmoid) ----
    float z = b2cp[0];
#pragma unroll
    for (int k = 0; k < F; k++) z = fmaf(hcp[k], w2cp[k], z);
    float compliance = 1.0f / (1.0f + expf(-z));

    // ---- Murray's law violation ----
    float rp_ = radii[ii];
    float r1_ = radii[c1];
    float r2_ = radii[c2];
    float pr3 = rp_ * rp_ * rp_;
    float viol = fabsf(r1_ * r1_ * r1_ + r2_ * r2_ * r2_ - pr3) / pr3;

    bool active = live && valid && (types[ii] == 1);
    bool upd = active && (viol > VIOL_THRESH);
    float gate = upd ? corr : 0.f;

    // ---- write updated features ----
    if (live) {
        const float4* fp4 = (const float4*)(feat + (size_t)ii * F);
        float4* op4 = (float4*)(out + (size_t)ii * F);
#pragma unroll
        for (int q = 0; q < F / 4; q++) {
            float4 v = fp4[q];
            float4 r;
            r.x = v.x + 0.1f * gate * tanhf(v.x);
            r.y = v.y + 0.1f * gate * tanhf(v.y);
            r.z = v.z + 0.1f * gate * tanhf(v.z);
            r.w = v.w + 0.1f * gate * tanhf(v.w);
            op4[q] = r;
        }
    }

    // ---- reductions: sum(viol|active), sum(compliance|active), count(active) ----
    float sv = active ? viol : 0.f;
    float sc = active ? compliance : 0.f;
    int   ct = active ? 1 : 0;
#pragma unroll
    for (int off = 32; off > 0; off >>= 1) {
        sv += __shfl_down(sv, off);
        sc += __shfl_down(sc, off);
        ct += __shfl_down(ct, off);
    }
    if ((threadIdx.x & 63) == 0) {
        atomicAdd(&accf[0], sv);
        atomicAdd(&accf[1], sc);
        atomicAdd(acci, ct);
    }
}

__global__ void finalize_kernel(const float* __restrict__ accf, const int* __restrict__ acci,
                                float* __restrict__ out_scalars) {
    if (threadIdx.x == 0) {
        int c = acci[0];
        float d = (float)(c > 1 ? c : 1);
        out_scalars[0] = accf[0] / d;
        out_scalars[1] = accf[1] / d;
    }
}

extern "C" void kernel_launch(void* const* d_in, const int* in_sizes, int n_in,
                              void* d_out, int out_size, void* d_ws, size_t ws_size,
                              hipStream_t stream) {
    const float* feat  = (const float*)d_in[0];
    const float* radii = (const float*)d_in[1];
    const float* w1rc  = (const float*)d_in[2];
    const float* b1rc  = (const float*)d_in[3];
    const float* w2rc  = (const float*)d_in[4];
    const float* b2rc  = (const float*)d_in[5];
    const float* w3rc  = (const float*)d_in[6];
    const float* b3rc  = (const float*)d_in[7];
    const float* w1cp  = (const float*)d_in[8];
    const float* b1cp  = (const float*)d_in[9];
    const float* w2cp  = (const float*)d_in[10];
    const float* b2cp  = (const float*)d_in[11];
    const int*   eidx  = (const int*)d_in[12];
    const int*   types = (const int*)d_in[13];

    int n = in_sizes[0] / F;          // 300000
    int m = in_sizes[12] / 2;         // 3000000

    int*   min1 = (int*)d_ws;
    int*   min2 = min1 + n;
    float* accf = (float*)(min2 + n);
    int*   acci = (int*)(accf + 2);

    float* out         = (float*)d_out;
    float* out_scalars = out + (size_t)n * F;

    int bs = 256;
    init_kernel<<<(n + bs - 1) / bs, bs, 0, stream>>>(min1, min2, accf, acci, n);
    edge_min1_kernel<<<(m + bs - 1) / bs, bs, 0, stream>>>(eidx, eidx + m, min1, m);
    edge_min2_kernel<<<(m + bs - 1) / bs, bs, 0, stream>>>(eidx, eidx + m, min1, min2, m);
    node_kernel<<<(n + bs - 1) / bs, bs, 0, stream>>>(
        feat, radii, w1rc, b1rc, w2rc, b2rc, w3rc, b3rc,
        w1cp, b1cp, w2cp, b2cp, types, min1, min2, out, accf, acci, n);
    finalize_kernel<<<1, 64, 0, stream>>>(accf, acci, out_scalars);
}

// Round 2
// 3967.869 us; speedup vs baseline: 1.2886x; 1.2886x over previous
//
#include <hip/hip_runtime.h>
#include <math.h>

#define F 64
#define VIOL_THRESH 0.2f

__global__ void init_kernel(int* __restrict__ min1, int* __restrict__ min2,
                            float* __restrict__ accf, int* __restrict__ acci, int n) {
    int i = blockIdx.x * blockDim.x + threadIdx.x;
    if (i < n) { min1[i] = n; min2[i] = n; }
    if (i == 0) { accf[0] = 0.f; accf[1] = 0.f; acci[0] = 0; }
}

__global__ void edge_min1_kernel(const int* __restrict__ e0, const int* __restrict__ e1,
                                 int* __restrict__ min1, int m) {
    int j = blockIdx.x * blockDim.x + threadIdx.x;
    if (j >= m) return;
    int u = e0[j], v = e1[j];
    if (u != v) {
        atomicMin(&min1[u], v);
        atomicMin(&min1[v], u);
    }
}

__global__ void edge_min2_kernel(const int* __restrict__ e0, const int* __restrict__ e1,
                                 const int* __restrict__ min1, int* __restrict__ min2, int m) {
    int j = blockIdx.x * blockDim.x + threadIdx.x;
    if (j >= m) return;
    int u = e0[j], v = e1[j];
    if (u != v) {
        if (v != min1[u]) atomicMin(&min2[u], v);
        if (u != min1[v]) atomicMin(&min2[v], u);
    }
}

__global__ __launch_bounds__(256, 4)
void node_kernel(const float* __restrict__ feat, const float* __restrict__ radii,
                 const float* __restrict__ w1rc, const float* __restrict__ b1rc,
                 const float* __restrict__ w2rc, const float* __restrict__ b2rc,
                 const float* __restrict__ w3rc, const float* __restrict__ b3rc,
                 const float* __restrict__ w1cp, const float* __restrict__ b1cp,
                 const float* __restrict__ w2cp, const float* __restrict__ b2cp,
                 const int* __restrict__ types,
                 const int* __restrict__ min1, const int* __restrict__ min2,
                 float* __restrict__ out, float* __restrict__ accf, int* __restrict__ acci,
                 int n) {
    int i = blockIdx.x * blockDim.x + threadIdx.x;
    bool live = i < n;
    int ii = live ? i : (n - 1);

    int m1 = min1[ii];
    int m2 = min2[ii];
    bool valid = m2 < n;
    int c1 = m1 < n ? m1 : (n - 1);
    int c2 = m2 < n ? m2 : (n - 1);

    const float* row0 = feat + (size_t)ii * F;
    const float* row1 = feat + (size_t)c1 * F;
    const float* row2 = feat + (size_t)c2 * F;

    // ================= Pass A: radius-corrector MLP =================
    float hacc[F];
#pragma unroll
    for (int o = 0; o < F; o++) hacc[o] = b1rc[o];

#pragma unroll
    for (int part = 0; part < 3; part++) {
        const float4* rp = (const float4*)((part == 0) ? row0 : ((part == 1) ? row1 : row2));
        const float* w = w1rc + (size_t)part * F * F;   // [k_local][o]
#pragma unroll
        for (int q = 0; q < 4; q++) {                    // 16-feature chunks
            float cv[16];
            float4 a0 = rp[q * 4 + 0];
            float4 a1 = rp[q * 4 + 1];
            float4 a2 = rp[q * 4 + 2];
            float4 a3 = rp[q * 4 + 3];
            cv[0] = a0.x;  cv[1] = a0.y;  cv[2] = a0.z;  cv[3] = a0.w;
            cv[4] = a1.x;  cv[5] = a1.y;  cv[6] = a1.z;  cv[7] = a1.w;
            cv[8] = a2.x;  cv[9] = a2.y;  cv[10] = a2.z; cv[11] = a2.w;
            cv[12] = a3.x; cv[13] = a3.y; cv[14] = a3.z; cv[15] = a3.w;
#pragma unroll
            for (int j = 0; j < 16; j++) {
                const float* wk = w + (size_t)(q * 16 + j) * F;
#pragma unroll
                for (int o = 0; o < F; o++)
                    hacc[o] = fmaf(cv[j], wk[o], hacc[o]);
            }
        }
    }
#pragma unroll
    for (int o = 0; o < F; o++) hacc[o] = fmaxf(hacc[o], 0.f);

    float corr = b3rc[0];
#pragma unroll
    for (int o = 0; o < 32; o++) {
        float s = b2rc[o];
#pragma unroll
        for (int k = 0; k < F; k++) s = fmaf(hacc[k], w2rc[k * 32 + o], s);
        s = fmaxf(s, 0.f);
        corr = fmaf(s, w3rc[o], corr);
    }

    // ================= Pass B: compliance MLP =================
#pragma unroll
    for (int o = 0; o < F; o++) hacc[o] = b1cp[o];

#pragma unroll
    for (int part = 0; part < 3; part++) {
        const float4* rp = (const float4*)((part == 0) ? row0 : ((part == 1) ? row1 : row2));
        const float* w = w1cp + (size_t)part * F * F;
#pragma unroll
        for (int q = 0; q < 4; q++) {
            float cv[16];
            float4 a0 = rp[q * 4 + 0];
            float4 a1 = rp[q * 4 + 1];
            float4 a2 = rp[q * 4 + 2];
            float4 a3 = rp[q * 4 + 3];
            cv[0] = a0.x;  cv[1] = a0.y;  cv[2] = a0.z;  cv[3] = a0.w;
            cv[4] = a1.x;  cv[5] = a1.y;  cv[6] = a1.z;  cv[7] = a1.w;
            cv[8] = a2.x;  cv[9] = a2.y;  cv[10] = a2.z; cv[11] = a2.w;
            cv[12] = a3.x; cv[13] = a3.y; cv[14] = a3.z; cv[15] = a3.w;
#pragma unroll
            for (int j = 0; j < 16; j++) {
                const float* wk = w + (size_t)(q * 16 + j) * F;
#pragma unroll
                for (int o = 0; o < F; o++)
                    hacc[o] = fmaf(cv[j], wk[o], hacc[o]);
            }
        }
    }

    float z = b2cp[0];
#pragma unroll
    for (int k = 0; k < F; k++) z = fmaf(fmaxf(hacc[k], 0.f), w2cp[k], z);
    float compliance = 1.0f / (1.0f + expf(-z));

    // ================= Murray's law violation =================
    float rp_ = radii[ii];
    float r1_ = radii[c1];
    float r2_ = radii[c2];
    float pr3 = rp_ * rp_ * rp_;
    float viol = fabsf(r1_ * r1_ * r1_ + r2_ * r2_ * r2_ - pr3) / pr3;

    bool active = live && valid && (types[ii] == 1);
    bool upd = active && (viol > VIOL_THRESH);
    float gate = upd ? corr : 0.f;

    // ================= write updated features =================
    if (live) {
        const float4* fp4 = (const float4*)row0;
        float4* op4 = (float4*)(out + (size_t)ii * F);
#pragma unroll
        for (int q = 0; q < F / 4; q++) {
            float4 v = fp4[q];
            float4 r;
            r.x = v.x + 0.1f * gate * tanhf(v.x);
            r.y = v.y + 0.1f * gate * tanhf(v.y);
            r.z = v.z + 0.1f * gate * tanhf(v.z);
            r.w = v.w + 0.1f * gate * tanhf(v.w);
            op4[q] = r;
        }
    }

    // ================= reductions =================
    float sv = active ? viol : 0.f;
    float sc = active ? compliance : 0.f;
    int   ct = active ? 1 : 0;
#pragma unroll
    for (int off = 32; off > 0; off >>= 1) {
        sv += __shfl_down(sv, off);
        sc += __shfl_down(sc, off);
        ct += __shfl_down(ct, off);
    }
    if ((threadIdx.x & 63) == 0) {
        atomicAdd(&accf[0], sv);
        atomicAdd(&accf[1], sc);
        atomicAdd(acci, ct);
    }
}

__global__ void finalize_kernel(const float* __restrict__ accf, const int* __restrict__ acci,
                                float* __restrict__ out_scalars) {
    if (threadIdx.x == 0) {
        int c = acci[0];
        float d = (float)(c > 1 ? c : 1);
        out_scalars[0] = accf[0] / d;
        out_scalars[1] = accf[1] / d;
    }
}

extern "C" void kernel_launch(void* const* d_in, const int* in_sizes, int n_in,
                              void* d_out, int out_size, void* d_ws, size_t ws_size,
                              hipStream_t stream) {
    const float* feat  = (const float*)d_in[0];
    const float* radii = (const float*)d_in[1];
    const float* w1rc  = (const float*)d_in[2];
    const float* b1rc  = (const float*)d_in[3];
    const float* w2rc  = (const float*)d_in[4];
    const float* b2rc  = (const float*)d_in[5];
    const float* w3rc  = (const float*)d_in[6];
    const float* b3rc  = (const float*)d_in[7];
    const float* w1cp  = (const float*)d_in[8];
    const float* b1cp  = (const float*)d_in[9];
    const float* w2cp  = (const float*)d_in[10];
    const float* b2cp  = (const float*)d_in[11];
    const int*   eidx  = (const int*)d_in[12];
    const int*   types = (const int*)d_in[13];

    int n = in_sizes[0] / F;          // 300000
    int m = in_sizes[12] / 2;         // 3000000

    int*   min1 = (int*)d_ws;
    int*   min2 = min1 + n;
    float* accf = (float*)(min2 + n);
    int*   acci = (int*)(accf + 2);

    float* out         = (float*)d_out;
    float* out_scalars = out + (size_t)n * F;

    int bs = 256;
    init_kernel<<<(n + bs - 1) / bs, bs, 0, stream>>>(min1, min2, accf, acci, n);
    edge_min1_kernel<<<(m + bs - 1) / bs, bs, 0, stream>>>(eidx, eidx + m, min1, m);
    edge_min2_kernel<<<(m + bs - 1) / bs, bs, 0, stream>>>(eidx, eidx + m, min1, min2, m);
    node_kernel<<<(n + bs - 1) / bs, bs, 0, stream>>>(
        feat, radii, w1rc, b1rc, w2rc, b2rc, w3rc, b3rc,
        w1cp, b1cp, w2cp, b2cp, types, min1, min2, out, accf, acci, n);
    finalize_kernel<<<1, 64, 0, stream>>>(accf, acci, out_scalars);
}

// Round 3
// 1112.349 us; speedup vs baseline: 4.5964x; 3.5671x over previous
//
#include <hip/hip_runtime.h>
#include <math.h>

#define F 64
#define VIOL_THRESH 0.2f

__global__ void init_kernel(int* __restrict__ min1, int* __restrict__ min2,
                            float* __restrict__ accf, int* __restrict__ acci, int n) {
    int i = blockIdx.x * blockDim.x + threadIdx.x;
    if (i < n) { min1[i] = n; min2[i] = n; }
    if (i == 0) { accf[0] = 0.f; accf[1] = 0.f; acci[0] = 0; }
}

__device__ __forceinline__ void upd_min1(int u, int v, int* __restrict__ min1) {
    if (u != v) {
        if (v < min1[u]) atomicMin(&min1[u], v);
        if (u < min1[v]) atomicMin(&min1[v], u);
    }
}

__global__ void edge_min1_kernel(const int* __restrict__ e0, const int* __restrict__ e1,
                                 int* __restrict__ min1, int m) {
    int t = blockIdx.x * blockDim.x + threadIdx.x;
    int base = t * 4;
    if (base >= m) return;
    if (base + 4 <= m) {
        int4 u4 = *(const int4*)(e0 + base);
        int4 v4 = *(const int4*)(e1 + base);
        upd_min1(u4.x, v4.x, min1);
        upd_min1(u4.y, v4.y, min1);
        upd_min1(u4.z, v4.z, min1);
        upd_min1(u4.w, v4.w, min1);
    } else {
        for (int j = base; j < m; j++) upd_min1(e0[j], e1[j], min1);
    }
}

__device__ __forceinline__ void upd_min2(int u, int v, const int* __restrict__ min1,
                                         int* __restrict__ min2) {
    if (u != v) {
        if (v != min1[u] && v < min2[u]) atomicMin(&min2[u], v);
        if (u != min1[v] && u < min2[v]) atomicMin(&min2[v], u);
    }
}

__global__ void edge_min2_kernel(const int* __restrict__ e0, const int* __restrict__ e1,
                                 const int* __restrict__ min1, int* __restrict__ min2, int m) {
    int t = blockIdx.x * blockDim.x + threadIdx.x;
    int base = t * 4;
    if (base >= m) return;
    if (base + 4 <= m) {
        int4 u4 = *(const int4*)(e0 + base);
        int4 v4 = *(const int4*)(e1 + base);
        upd_min2(u4.x, v4.x, min1, min2);
        upd_min2(u4.y, v4.y, min1, min2);
        upd_min2(u4.z, v4.z, min1, min2);
        upd_min2(u4.w, v4.w, min1, min2);
    } else {
        for (int j = base; j < m; j++) upd_min2(e0[j], e1[j], min1, min2);
    }
}

__global__ __launch_bounds__(256)
void node_kernel(const float* __restrict__ feat, const float* __restrict__ radii,
                 const float* __restrict__ w1rc, const float* __restrict__ b1rc,
                 const float* __restrict__ w2rc, const float* __restrict__ b2rc,
                 const float* __restrict__ w3rc, const float* __restrict__ b3rc,
                 const float* __restrict__ w1cp, const float* __restrict__ b1cp,
                 const float* __restrict__ w2cp, const float* __restrict__ b2cp,
                 const int* __restrict__ types,
                 const int* __restrict__ min1, const int* __restrict__ min2,
                 float* __restrict__ out, float* __restrict__ accf, int* __restrict__ acci,
                 int n) {
    int i = blockIdx.x * blockDim.x + threadIdx.x;
    bool live = i < n;
    int ii = live ? i : (n - 1);

    int m1 = min1[ii];
    int m2 = min2[ii];
    bool valid = m2 < n;
    int c1 = m1 < n ? m1 : (n - 1);
    int c2 = m2 < n ? m2 : (n - 1);

    const float* row0 = feat + (size_t)ii * F;
    const float* row1 = feat + (size_t)c1 * F;
    const float* row2 = feat + (size_t)c2 * F;

    // ---- fused layer-1 of BOTH MLPs (one pass over the gathered features) ----
    float hrc[F], hcp[F];
#pragma unroll
    for (int o = 0; o < F; o++) { hrc[o] = b1rc[o]; hcp[o] = b1cp[o]; }

#pragma unroll
    for (int part = 0; part < 3; part++) {         // unrolled -> row ptr selected statically
        const float4* rp = (const float4*)((part == 0) ? row0 : ((part == 1) ? row1 : row2));
        const float* wr0 = w1rc + (size_t)part * F * F;   // [k_local][o]
        const float* wc0 = w1cp + (size_t)part * F * F;
        for (int q = 0; q < F / 4; q++) {          // RUNTIME loop: small code, no I-thrash
            float4 v = rp[q];
            const float* wr = wr0 + (size_t)q * 4 * F;
            const float* wc = wc0 + (size_t)q * 4 * F;
#pragma unroll
            for (int j = 0; j < 4; j++) {
                float x = (j == 0) ? v.x : (j == 1) ? v.y : (j == 2) ? v.z : v.w;
#pragma unroll
                for (int o = 0; o < F; o++) {
                    hrc[o] = fmaf(x, wr[j * F + o], hrc[o]);
                    hcp[o] = fmaf(x, wc[j * F + o], hcp[o]);
                }
            }
        }
    }

    // ---- rc layer-2 (64->32 relu) fused with layer-3 (32->1) ----
    float corr = b3rc[0];
#pragma unroll
    for (int o = 0; o < 32; o++) {
        float s = b2rc[o];
#pragma unroll
        for (int k = 0; k < F; k++) s = fmaf(fmaxf(hrc[k], 0.f), w2rc[k * 32 + o], s);
        s = fmaxf(s, 0.f);
        corr = fmaf(s, w3rc[o], corr);
    }

    // ---- cp output (64->1, sigmoid) ----
    float z = b2cp[0];
#pragma unroll
    for (int k = 0; k < F; k++) z = fmaf(fmaxf(hcp[k], 0.f), w2cp[k], z);
    float compliance = 1.0f / (1.0f + expf(-z));

    // ---- Murray's law violation ----
    float rp_ = radii[ii];
    float r1_ = radii[c1];
    float r2_ = radii[c2];
    float pr3 = rp_ * rp_ * rp_;
    float viol = fabsf(r1_ * r1_ * r1_ + r2_ * r2_ * r2_ - pr3) / pr3;

    bool active = live && valid && (types[ii] == 1);
    bool upd = active && (viol > VIOL_THRESH);
    float gate = upd ? corr : 0.f;

    // ---- write updated features ----
    if (live) {
        const float4* fp4 = (const float4*)row0;
        float4* op4 = (float4*)(out + (size_t)ii * F);
        for (int q = 0; q < F / 4; q++) {          // runtime loop (code size)
            float4 v = fp4[q];
            float4 r;
            r.x = v.x + 0.1f * gate * tanhf(v.x);
            r.y = v.y + 0.1f * gate * tanhf(v.y);
            r.z = v.z + 0.1f * gate * tanhf(v.z);
            r.w = v.w + 0.1f * gate * tanhf(v.w);
            op4[q] = r;
        }
    }

    // ---- reductions ----
    float sv = active ? viol : 0.f;
    float sc = active ? compliance : 0.f;
    int   ct = active ? 1 : 0;
#pragma unroll
    for (int off = 32; off > 0; off >>= 1) {
        sv += __shfl_down(sv, off);
        sc += __shfl_down(sc, off);
        ct += __shfl_down(ct, off);
    }
    if ((threadIdx.x & 63) == 0) {
        atomicAdd(&accf[0], sv);
        atomicAdd(&accf[1], sc);
        atomicAdd(acci, ct);
    }
}

__global__ void finalize_kernel(const float* __restrict__ accf, const int* __restrict__ acci,
                                float* __restrict__ out_scalars) {
    if (threadIdx.x == 0) {
        int c = acci[0];
        float d = (float)(c > 1 ? c : 1);
        out_scalars[0] = accf[0] / d;
        out_scalars[1] = accf[1] / d;
    }
}

extern "C" void kernel_launch(void* const* d_in, const int* in_sizes, int n_in,
                              void* d_out, int out_size, void* d_ws, size_t ws_size,
                              hipStream_t stream) {
    const float* feat  = (const float*)d_in[0];
    const float* radii = (const float*)d_in[1];
    const float* w1rc  = (const float*)d_in[2];
    const float* b1rc  = (const float*)d_in[3];
    const float* w2rc  = (const float*)d_in[4];
    const float* b2rc  = (const float*)d_in[5];
    const float* w3rc  = (const float*)d_in[6];
    const float* b3rc  = (const float*)d_in[7];
    const float* w1cp  = (const float*)d_in[8];
    const float* b1cp  = (const float*)d_in[9];
    const float* w2cp  = (const float*)d_in[10];
    const float* b2cp  = (const float*)d_in[11];
    const int*   eidx  = (const int*)d_in[12];
    const int*   types = (const int*)d_in[13];

    int n = in_sizes[0] / F;          // 300000
    int m = in_sizes[12] / 2;         // 3000000

    int*   min1 = (int*)d_ws;
    int*   min2 = min1 + n;
    float* accf = (float*)(min2 + n);
    int*   acci = (int*)(accf + 2);

    float* out         = (float*)d_out;
    float* out_scalars = out + (size_t)n * F;

    int bs = 256;
    init_kernel<<<(n + bs - 1) / bs, bs, 0, stream>>>(min1, min2, accf, acci, n);
    int mt = (m + 3) / 4;
    edge_min1_kernel<<<(mt + bs - 1) / bs, bs, 0, stream>>>(eidx, eidx + m, min1, m);
    edge_min2_kernel<<<(mt + bs - 1) / bs, bs, 0, stream>>>(eidx, eidx + m, min1, min2, m);
    node_kernel<<<(n + bs - 1) / bs, bs, 0, stream>>>(
        feat, radii, w1rc, b1rc, w2rc, b2rc, w3rc, b3rc,
        w1cp, b1cp, w2cp, b2cp, types, min1, min2, out, accf, acci, n);
    finalize_kernel<<<1, 64, 0, stream>>>(accf, acci, out_scalars);
}

// Round 4
// 648.157 us; speedup vs baseline: 7.8882x; 1.7162x over previous
//
#include <hip/hip_runtime.h>
#include <math.h>

#define F 64
#define VIOL_THRESH 0.2f
#define BLK_NODES 128
#define WT1_ROWB 400   // 200 bf16 per row (192 + pad)
#define H_ROWB   272   // 136 bf16 per row (128 + pad)
#define WT2_ROWB 272   // 136 bf16 per row (128 + pad)

typedef float  f32x4  __attribute__((ext_vector_type(4)));
typedef short  bf16x8 __attribute__((ext_vector_type(8)));

__device__ __forceinline__ short f2bf(float f) {
    unsigned u = __builtin_bit_cast(unsigned, f);
    unsigned r = (u + 0x7fffu + ((u >> 16) & 1u)) >> 16;
    return (short)r;
}

__global__ void init_kernel(int* __restrict__ min1, int* __restrict__ min2,
                            float* __restrict__ accf, int* __restrict__ acci, int n) {
    int i = blockIdx.x * blockDim.x + threadIdx.x;
    if (i < n) { min1[i] = n; min2[i] = n; }
    if (i == 0) { accf[0] = 0.f; accf[1] = 0.f; acci[0] = 0; }
}

__device__ __forceinline__ void upd_min1(int u, int v, int* __restrict__ min1) {
    if (u != v) {
        if (v < min1[u]) atomicMin(&min1[u], v);
        if (u < min1[v]) atomicMin(&min1[v], u);
    }
}

__global__ void edge_min1_kernel(const int* __restrict__ e0, const int* __restrict__ e1,
                                 int* __restrict__ min1, int m) {
    int t = blockIdx.x * blockDim.x + threadIdx.x;
    int base = t * 4;
    if (base >= m) return;
    if (base + 4 <= m) {
        int4 u4 = *(const int4*)(e0 + base);
        int4 v4 = *(const int4*)(e1 + base);
        upd_min1(u4.x, v4.x, min1);
        upd_min1(u4.y, v4.y, min1);
        upd_min1(u4.z, v4.z, min1);
        upd_min1(u4.w, v4.w, min1);
    } else {
        for (int j = base; j < m; j++) upd_min1(e0[j], e1[j], min1);
    }
}

__device__ __forceinline__ void upd_min2(int u, int v, const int* __restrict__ min1,
                                         int* __restrict__ min2) {
    if (u != v) {
        if (v != min1[u] && v < min2[u]) atomicMin(&min2[u], v);
        if (u != min1[v] && u < min2[v]) atomicMin(&min2[v], u);
    }
}

__global__ void edge_min2_kernel(const int* __restrict__ e0, const int* __restrict__ e1,
                                 const int* __restrict__ min1, int* __restrict__ min2, int m) {
    int t = blockIdx.x * blockDim.x + threadIdx.x;
    int base = t * 4;
    if (base >= m) return;
    if (base + 4 <= m) {
        int4 u4 = *(const int4*)(e0 + base);
        int4 v4 = *(const int4*)(e1 + base);
        upd_min2(u4.x, v4.x, min1, min2);
        upd_min2(u4.y, v4.y, min1, min2);
        upd_min2(u4.z, v4.z, min1, min2);
        upd_min2(u4.w, v4.w, min1, min2);
    } else {
        for (int j = base; j < m; j++) upd_min2(e0[j], e1[j], min1, min2);
    }
}

__global__ __launch_bounds__(256)
void node_kernel(const float* __restrict__ feat, const float* __restrict__ radii,
                 const float* __restrict__ w1rc, const float* __restrict__ b1rc,
                 const float* __restrict__ w2rc, const float* __restrict__ b2rc,
                 const float* __restrict__ w3rc, const float* __restrict__ b3rc,
                 const float* __restrict__ w1cp, const float* __restrict__ b1cp,
                 const float* __restrict__ w2cp, const float* __restrict__ b2cp,
                 const int* __restrict__ types,
                 const int* __restrict__ min1, const int* __restrict__ min2,
                 float* __restrict__ out, float* __restrict__ accf, int* __restrict__ acci,
                 int n) {
    __shared__ __align__(16) char bufA[128 * WT1_ROWB];   // Wt1 (51200 B) -> later H (128x136 bf16)
    __shared__ __align__(16) char bufB[48 * WT2_ROWB];    // Wt2 (13056 B) -> later corr/z/gate

    int tid = threadIdx.x;
    int blk = blockIdx.x;

    // ---------- stage Wt1[o][k] = W1[k][o] (bf16, o-major, padded) ----------
    {
        int o = tid & 127;
        int h2 = tid >> 7;                 // 0/1: which K-half
        const float* src = (o < 64) ? (w1rc + o) : (w1cp + (o - 64));
        short* dst = (short*)(bufA + o * WT1_ROWB);
        for (int k = h2 * 96; k < h2 * 96 + 96; k++)
            dst[k] = f2bf(src[(size_t)k * 64]);
    }
    // ---------- stage Wt2big[o][k] (48 x 128, block-diagonal) ----------
    for (int idx = tid; idx < 48 * 128; idx += 256) {
        int o = idx >> 7, k = idx & 127;
        float v = 0.f;
        if (o < 32)       { if (k < 64) v = w2rc[k * 32 + o]; }
        else if (o == 32) { if (k >= 64) v = w2cp[k - 64]; }
        *(short*)(bufB + o * WT2_ROWB + k * 2) = f2bf(v);
    }
    __syncthreads();

    int lane = tid & 63;
    int w = tid >> 6;           // wave 0..3
    int lm = lane & 15;         // m/n fragment index
    int lg = lane >> 4;         // k-group 0..3
    int wnb = w * 32;           // wave node base (local)

    // node ids per (m-tile, part)
    int nid[2][3];
#pragma unroll
    for (int mt = 0; mt < 2; mt++) {
        int g = blk * BLK_NODES + wnb + mt * 16 + lm;
        int ii = (g < n) ? g : (n - 1);
        int m1 = min1[ii], m2 = min2[ii];
        nid[mt][0] = ii;
        nid[mt][1] = (m1 < n) ? m1 : (n - 1);
        nid[mt][2] = (m2 < n) ? m2 : (n - 1);
    }

    // ---------- layer 1: H[128 nodes][128 outs] = X[.,192] @ W1 ----------
    f32x4 zero4 = {0.f, 0.f, 0.f, 0.f};
    f32x4 acc[2][8];
#pragma unroll
    for (int mt = 0; mt < 2; mt++)
#pragma unroll
        for (int nt = 0; nt < 8; nt++) acc[mt][nt] = zero4;

#pragma unroll
    for (int s = 0; s < 6; s++) {
        int part = s >> 1;
        int off = (s & 1) * 32 + lg * 8;
        bf16x8 af[2];
#pragma unroll
        for (int mt = 0; mt < 2; mt++) {
            const float* rp = feat + (size_t)nid[mt][part] * F + off;
            float4 f0 = *(const float4*)rp;
            float4 f1 = *(const float4*)(rp + 4);
            bf16x8 a;
            a[0] = f2bf(f0.x); a[1] = f2bf(f0.y); a[2] = f2bf(f0.z); a[3] = f2bf(f0.w);
            a[4] = f2bf(f1.x); a[5] = f2bf(f1.y); a[6] = f2bf(f1.z); a[7] = f2bf(f1.w);
            af[mt] = a;
        }
#pragma unroll
        for (int nt = 0; nt < 8; nt++) {
            bf16x8 b = *(const bf16x8*)(bufA + (lm + 16 * nt) * WT1_ROWB + s * 64 + lg * 16);
            acc[0][nt] = __builtin_amdgcn_mfma_f32_16x16x32_bf16(af[0], b, acc[0][nt], 0, 0, 0);
            acc[1][nt] = __builtin_amdgcn_mfma_f32_16x16x32_bf16(af[1], b, acc[1][nt], 0, 0, 0);
        }
    }

    __syncthreads();   // everyone done reading Wt1; reuse bufA for H

    // H = relu(acc + b1) as bf16, rows padded to 136
#pragma unroll
    for (int nt = 0; nt < 8; nt++) {
        int o = lm + 16 * nt;
        float b1v = (o < 64) ? b1rc[o] : b1cp[o - 64];
#pragma unroll
        for (int mt = 0; mt < 2; mt++) {
#pragma unroll
            for (int r = 0; r < 4; r++) {
                int node = wnb + mt * 16 + lg * 4 + r;
                float hv = fmaxf(acc[mt][nt][r] + b1v, 0.f);
                *(short*)(bufA + node * H_ROWB + o * 2) = f2bf(hv);
            }
        }
    }
    __syncthreads();

    // ---------- layer 2: [128 nodes][33] = H @ W2big ----------
    f32x4 acc2[2][3];
#pragma unroll
    for (int mt = 0; mt < 2; mt++)
#pragma unroll
        for (int nt = 0; nt < 3; nt++) acc2[mt][nt] = zero4;

#pragma unroll
    for (int s = 0; s < 4; s++) {
        bf16x8 af2[2];
#pragma unroll
        for (int mt = 0; mt < 2; mt++)
            af2[mt] = *(const bf16x8*)(bufA + (wnb + mt * 16 + lm) * H_ROWB + s * 64 + lg * 16);
#pragma unroll
        for (int nt = 0; nt < 3; nt++) {
            bf16x8 b = *(const bf16x8*)(bufB + (lm + 16 * nt) * WT2_ROWB + s * 64 + lg * 16);
            acc2[0][nt] = __builtin_amdgcn_mfma_f32_16x16x32_bf16(af2[0], b, acc2[0][nt], 0, 0, 0);
            acc2[1][nt] = __builtin_amdgcn_mfma_f32_16x16x32_bf16(af2[1], b, acc2[1][nt], 0, 0, 0);
        }
    }

    __syncthreads();   // everyone done reading Wt2; reuse bufB
    float* corrArr = (float*)bufB;                 // [128]
    float* zArr    = (float*)(bufB + 512);         // [128]
    float* gateArr = (float*)(bufB + 1024);        // [128]

    // corr = b3 + sum_o relu(acc2 + b2rc[o]) * w3rc[o];  z = sum(acc2[nt=2]) + b2cp
#pragma unroll
    for (int mt = 0; mt < 2; mt++) {
#pragma unroll
        for (int r = 0; r < 4; r++) {
            float t = 0.f;
#pragma unroll
            for (int nt = 0; nt < 2; nt++) {
                int o = lm + 16 * nt;
                float s2v = fmaxf(acc2[mt][nt][r] + b2rc[o], 0.f);
                t = fmaf(s2v, w3rc[o], t);
            }
            float zz = acc2[mt][2][r];   // cols 33..47 are exact zeros
#pragma unroll
            for (int msk = 1; msk < 16; msk <<= 1) {
                t  += __shfl_xor(t, msk);
                zz += __shfl_xor(zz, msk);
            }
            if (lm == 0) {
                int node = wnb + mt * 16 + lg * 4 + r;
                corrArr[node] = t + b3rc[0];
                zArr[node]    = zz + b2cp[0];
            }
        }
    }
    __syncthreads();

    // ---------- epilogue: viol / gate / averages ----------
    float sv = 0.f, sc = 0.f; int ct = 0;
    if (tid < BLK_NODES) {
        int g = blk * BLK_NODES + tid;
        bool live = g < n;
        int ii = live ? g : (n - 1);
        int m1 = min1[ii], m2 = min2[ii];
        bool valid = m2 < n;
        int c1 = (m1 < n) ? m1 : (n - 1);
        int c2 = (m2 < n) ? m2 : (n - 1);
        float rp_ = radii[ii], r1_ = radii[c1], r2_ = radii[c2];
        float pr3 = rp_ * rp_ * rp_;
        float viol = fabsf(r1_ * r1_ * r1_ + r2_ * r2_ * r2_ - pr3) / pr3;
        bool active = live && valid && (types[ii] == 1);
        bool upd = active && (viol > VIOL_THRESH);
        float gate = upd ? corrArr[tid] : 0.f;
        gateArr[tid] = 0.1f * gate;
        if (active) {
            sv = viol;
            sc = 1.0f / (1.0f + expf(-zArr[tid]));
            ct = 1;
        }
    }
#pragma unroll
    for (int off = 32; off > 0; off >>= 1) {
        sv += __shfl_down(sv, off);
        sc += __shfl_down(sc, off);
        ct += __shfl_down(ct, off);
    }
    if (lane == 0 && (sv != 0.f || sc != 0.f || ct != 0)) {
        atomicAdd(&accf[0], sv);
        atomicAdd(&accf[1], sc);
        atomicAdd(acci, ct);
    }
    __syncthreads();

    // output write: 2 threads per node, 32 floats each
    {
        int node = tid >> 1;
        int g = blk * BLK_NODES + node;
        if (g < n) {
            float gate01 = gateArr[node];
            int fo = (tid & 1) * 32;
            const float4* fp4 = (const float4*)(feat + (size_t)g * F + fo);
            float4* op4 = (float4*)(out + (size_t)g * F + fo);
#pragma unroll
            for (int q = 0; q < 8; q++) {
                float4 v = fp4[q];
                float4 r;
                r.x = v.x + gate01 * tanhf(v.x);
                r.y = v.y + gate01 * tanhf(v.y);
                r.z = v.z + gate01 * tanhf(v.z);
                r.w = v.w + gate01 * tanhf(v.w);
                op4[q] = r;
            }
        }
    }
}

__global__ void finalize_kernel(const float* __restrict__ accf, const int* __restrict__ acci,
                                float* __restrict__ out_scalars) {
    if (threadIdx.x == 0) {
        int c = acci[0];
        float d = (float)(c > 1 ? c : 1);
        out_scalars[0] = accf[0] / d;
        out_scalars[1] = accf[1] / d;
    }
}

extern "C" void kernel_launch(void* const* d_in, const int* in_sizes, int n_in,
                              void* d_out, int out_size, void* d_ws, size_t ws_size,
                              hipStream_t stream) {
    const float* feat  = (const float*)d_in[0];
    const float* radii = (const float*)d_in[1];
    const float* w1rc  = (const float*)d_in[2];
    const float* b1rc  = (const float*)d_in[3];
    const float* w2rc  = (const float*)d_in[4];
    const float* b2rc  = (const float*)d_in[5];
    const float* w3rc  = (const float*)d_in[6];
    const float* b3rc  = (const float*)d_in[7];
    const float* w1cp  = (const float*)d_in[8];
    const float* b1cp  = (const float*)d_in[9];
    const float* w2cp  = (const float*)d_in[10];
    const float* b2cp  = (const float*)d_in[11];
    const int*   eidx  = (const int*)d_in[12];
    const int*   types = (const int*)d_in[13];

    int n = in_sizes[0] / F;          // 300000
    int m = in_sizes[12] / 2;         // 3000000

    int*   min1 = (int*)d_ws;
    int*   min2 = min1 + n;
    float* accf = (float*)(min2 + n);
    int*   acci = (int*)(accf + 2);

    float* out         = (float*)d_out;
    float* out_scalars = out + (size_t)n * F;

    int bs = 256;
    init_kernel<<<(n + bs - 1) / bs, bs, 0, stream>>>(min1, min2, accf, acci, n);
    int mt = (m + 3) / 4;
    edge_min1_kernel<<<(mt + bs - 1) / bs, bs, 0, stream>>>(eidx, eidx + m, min1, m);
    edge_min2_kernel<<<(mt + bs - 1) / bs, bs, 0, stream>>>(eidx, eidx + m, min1, min2, m);
    node_kernel<<<(n + BLK_NODES - 1) / BLK_NODES, bs, 0, stream>>>(
        feat, radii, w1rc, b1rc, w2rc, b2rc, w3rc, b3rc,
        w1cp, b1cp, w2cp, b2cp, types, min1, min2, out, accf, acci, n);
    finalize_kernel<<<1, 64, 0, stream>>>(accf, acci, out_scalars);
}

// Round 5
// 493.776 us; speedup vs baseline: 10.3545x; 1.3127x over previous
//
#include <hip/hip_runtime.h>
#include <math.h>

#define F 64
#define VIOL_THRESH 0.2f
#define BLK_NODES 128
#define H_ROWB 272   // 136 bf16 per row (128 + pad), 68 words ≡ 4 mod 32 banks -> 2-way (free)

typedef float  f32x4  __attribute__((ext_vector_type(4)));
typedef short  bf16x8 __attribute__((ext_vector_type(8)));

__device__ __forceinline__ short f2bf(float f) {
    unsigned u = __builtin_bit_cast(unsigned, f);
    unsigned r = (u + 0x7fffu + ((u >> 16) & 1u)) >> 16;
    return (short)r;
}

__global__ void init_kernel(unsigned long long* __restrict__ pairs,
                            float* __restrict__ accf, int* __restrict__ acci,
                            int n, unsigned long long sent) {
    int i = blockIdx.x * blockDim.x + threadIdx.x;
    if (i < n) pairs[i] = sent;
    if (i == 0) { accf[0] = 0.f; accf[1] = 0.f; acci[0] = 0; }
}

// wt1t[o][k]: o in [0,128) (64 rc outs | 64 cp outs), k in [0,192)
__global__ void prep_w1(const float* __restrict__ w1rc, const float* __restrict__ w1cp,
                        short* __restrict__ wt1t) {
    int o = blockIdx.x;                      // 0..127
    int k = blockIdx.y * 64 + threadIdx.x;   // 0..191
    const float* src = (o < 64) ? (w1rc + o) : (w1cp + (o - 64));
    wt1t[o * 192 + k] = f2bf(src[(size_t)k * 64]);
}

// wt2t[o][k]: 48 x 128 block-diagonal (rc 64->32 | cp-as-col32 64->1)
__global__ void prep_w2(const float* __restrict__ w2rc, const float* __restrict__ w2cp,
                        short* __restrict__ wt2t) {
    int o = blockIdx.x;                      // 0..47
    int k = blockIdx.y * 64 + threadIdx.x;   // 0..127
    float v = 0.f;
    if (o < 32)       { if (k < 64) v = w2rc[k * 32 + o]; }
    else if (o == 32) { if (k >= 64) v = w2cp[k - 64]; }
    wt2t[o * 128 + k] = f2bf(v);
}

__device__ __forceinline__ void ins2(unsigned long long* __restrict__ p, unsigned v) {
    unsigned long long cur = *p;             // stale-tolerant (monotone decreasing)
    while (true) {
        unsigned m1 = (unsigned)(cur >> 32);
        unsigned m2 = (unsigned)cur;
        unsigned nm1, nm2;
        if (v < m1)                   { nm1 = v;  nm2 = m1; }
        else if (v != m1 && v < m2)   { nm1 = m1; nm2 = v;  }
        else return;
        unsigned long long nw = ((unsigned long long)nm1 << 32) | nm2;
        unsigned long long prev = atomicCAS(p, cur, nw);
        if (prev == cur) return;
        cur = prev;
    }
}

__global__ void edge_pair_kernel(const int* __restrict__ e0, const int* __restrict__ e1,
                                 unsigned long long* __restrict__ pairs, int m) {
    int t = blockIdx.x * blockDim.x + threadIdx.x;
    int base = t * 4;
    if (base >= m) return;
    if (base + 4 <= m) {
        int4 u4 = *(const int4*)(e0 + base);
        int4 v4 = *(const int4*)(e1 + base);
        if (u4.x != v4.x) { ins2(&pairs[u4.x], v4.x); ins2(&pairs[v4.x], u4.x); }
        if (u4.y != v4.y) { ins2(&pairs[u4.y], v4.y); ins2(&pairs[v4.y], u4.y); }
        if (u4.z != v4.z) { ins2(&pairs[u4.z], v4.z); ins2(&pairs[v4.z], u4.z); }
        if (u4.w != v4.w) { ins2(&pairs[u4.w], v4.w); ins2(&pairs[v4.w], u4.w); }
    } else {
        for (int j = base; j < m; j++) {
            int u = e0[j], v = e1[j];
            if (u != v) { ins2(&pairs[u], v); ins2(&pairs[v], u); }
        }
    }
}

__global__ __launch_bounds__(256, 4)
void node_kernel(const float* __restrict__ feat, const float* __restrict__ radii,
                 const float* __restrict__ b1rc, const float* __restrict__ b2rc,
                 const float* __restrict__ w3rc, const float* __restrict__ b3rc,
                 const float* __restrict__ b1cp, const float* __restrict__ b2cp,
                 const short* __restrict__ wt1t, const short* __restrict__ wt2t,
                 const int* __restrict__ types,
                 const unsigned long long* __restrict__ pairs,
                 float* __restrict__ out, float* __restrict__ accf, int* __restrict__ acci,
                 int n) {
    __shared__ __align__(16) char Hbuf[BLK_NODES * H_ROWB];   // 34816 B
    __shared__ float corrArr[BLK_NODES];
    __shared__ float zArr[BLK_NODES];
    __shared__ float gateArr[BLK_NODES];

    int tid = threadIdx.x;
    int blk = blockIdx.x;
    int lane = tid & 63;
    int w = tid >> 6;           // wave 0..3
    int lm = lane & 15;
    int lg = lane >> 4;
    int wnb = w * 32;           // wave's local node base

    // node ids per (m-tile, part)
    int nid[2][3];
#pragma unroll
    for (int mt = 0; mt < 2; mt++) {
        int g = blk * BLK_NODES + wnb + mt * 16 + lm;
        int ii = (g < n) ? g : (n - 1);
        unsigned long long pr = pairs[ii];
        int m1 = (int)(pr >> 32);
        int m2 = (int)(unsigned)pr;
        nid[mt][0] = ii;
        nid[mt][1] = (m1 < n) ? m1 : (n - 1);
        nid[mt][2] = (m2 < n) ? m2 : (n - 1);
    }

    // ---------- layer 1: H[128 nodes][128 outs] ----------
    f32x4 zero4 = {0.f, 0.f, 0.f, 0.f};
    f32x4 acc[2][8];
#pragma unroll
    for (int mt = 0; mt < 2; mt++)
#pragma unroll
        for (int nt = 0; nt < 8; nt++) acc[mt][nt] = zero4;

#pragma unroll
    for (int s = 0; s < 6; s++) {
        int part = s >> 1;
        int off = (s & 1) * 32 + lg * 8;
        bf16x8 af[2];
#pragma unroll
        for (int mt = 0; mt < 2; mt++) {
            const float* rp = feat + (size_t)nid[mt][part] * F + off;
            float4 f0 = *(const float4*)rp;
            float4 f1 = *(const float4*)(rp + 4);
            bf16x8 a;
            a[0] = f2bf(f0.x); a[1] = f2bf(f0.y); a[2] = f2bf(f0.z); a[3] = f2bf(f0.w);
            a[4] = f2bf(f1.x); a[5] = f2bf(f1.y); a[6] = f2bf(f1.z); a[7] = f2bf(f1.w);
            af[mt] = a;
        }
#pragma unroll
        for (int nt = 0; nt < 8; nt++) {
            bf16x8 b = *(const bf16x8*)(wt1t + (lm + 16 * nt) * 192 + s * 32 + lg * 8);
            acc[0][nt] = __builtin_amdgcn_mfma_f32_16x16x32_bf16(af[0], b, acc[0][nt], 0, 0, 0);
            acc[1][nt] = __builtin_amdgcn_mfma_f32_16x16x32_bf16(af[1], b, acc[1][nt], 0, 0, 0);
        }
    }

    // H = relu(acc + b1) as bf16
#pragma unroll
    for (int nt = 0; nt < 8; nt++) {
        int o = lm + 16 * nt;
        float b1v = (o < 64) ? b1rc[o] : b1cp[o - 64];
#pragma unroll
        for (int mt = 0; mt < 2; mt++) {
#pragma unroll
            for (int r = 0; r < 4; r++) {
                int node = wnb + mt * 16 + lg * 4 + r;
                float hv = fmaxf(acc[mt][nt][r] + b1v, 0.f);
                *(short*)(Hbuf + node * H_ROWB + o * 2) = f2bf(hv);
            }
        }
    }
    __syncthreads();

    // ---------- layer 2: [128 nodes][33 of 48] ----------
    f32x4 acc2[2][3];
#pragma unroll
    for (int mt = 0; mt < 2; mt++)
#pragma unroll
        for (int nt = 0; nt < 3; nt++) acc2[mt][nt] = zero4;

#pragma unroll
    for (int s = 0; s < 4; s++) {
        bf16x8 af2[2];
#pragma unroll
        for (int mt = 0; mt < 2; mt++)
            af2[mt] = *(const bf16x8*)(Hbuf + (wnb + mt * 16 + lm) * H_ROWB + s * 64 + lg * 16);
#pragma unroll
        for (int nt = 0; nt < 3; nt++) {
            bf16x8 b = *(const bf16x8*)(wt2t + (lm + 16 * nt) * 128 + s * 32 + lg * 8);
            acc2[0][nt] = __builtin_amdgcn_mfma_f32_16x16x32_bf16(af2[0], b, acc2[0][nt], 0, 0, 0);
            acc2[1][nt] = __builtin_amdgcn_mfma_f32_16x16x32_bf16(af2[1], b, acc2[1][nt], 0, 0, 0);
        }
    }

    // corr / z per node
#pragma unroll
    for (int mt = 0; mt < 2; mt++) {
#pragma unroll
        for (int r = 0; r < 4; r++) {
            float t = 0.f;
#pragma unroll
            for (int nt = 0; nt < 2; nt++) {
                int o = lm + 16 * nt;
                float s2v = fmaxf(acc2[mt][nt][r] + b2rc[o], 0.f);
                t = fmaf(s2v, w3rc[o], t);
            }
            float zz = acc2[mt][2][r];   // cols 33..47 exact zeros
#pragma unroll
            for (int msk = 1; msk < 16; msk <<= 1) {
                t  += __shfl_xor(t, msk);
                zz += __shfl_xor(zz, msk);
            }
            if (lm == 0) {
                int node = wnb + mt * 16 + lg * 4 + r;
                corrArr[node] = t + b3rc[0];
                zArr[node]    = zz + b2cp[0];
            }
        }
    }
    __syncthreads();

    // ---------- epilogue: viol / gate / averages ----------
    float sv = 0.f, sc = 0.f; int ct = 0;
    if (tid < BLK_NODES) {
        int g = blk * BLK_NODES + tid;
        bool live = g < n;
        int ii = live ? g : (n - 1);
        unsigned long long pr = pairs[ii];
        int m1 = (int)(pr >> 32);
        int m2 = (int)(unsigned)pr;
        bool valid = m2 < n;
        int c1 = (m1 < n) ? m1 : (n - 1);
        int c2 = (m2 < n) ? m2 : (n - 1);
        float rp_ = radii[ii], r1_ = radii[c1], r2_ = radii[c2];
        float pr3 = rp_ * rp_ * rp_;
        float viol = fabsf(r1_ * r1_ * r1_ + r2_ * r2_ * r2_ - pr3) / pr3;
        bool active = live && valid && (types[ii] == 1);
        bool upd = active && (viol > VIOL_THRESH);
        float gate = upd ? corrArr[tid] : 0.f;
        gateArr[tid] = 0.1f * gate;
        if (active) {
            sv = viol;
            sc = 1.0f / (1.0f + expf(-zArr[tid]));
            ct = 1;
        }
    }
#pragma unroll
    for (int off = 32; off > 0; off >>= 1) {
        sv += __shfl_down(sv, off);
        sc += __shfl_down(sc, off);
        ct += __shfl_down(ct, off);
    }
    if (lane == 0 && (sv != 0.f || sc != 0.f || ct != 0)) {
        atomicAdd(&accf[0], sv);
        atomicAdd(&accf[1], sc);
        atomicAdd(acci, ct);
    }
    __syncthreads();

    // ---------- coalesced feature update: wave covers contiguous 8 KB ----------
    {
        size_t wbase = (size_t)(blk * BLK_NODES + wnb) * F;
        const float* fsrc = feat + wbase;
        float* fdst = out + wbase;
#pragma unroll
        for (int q = 0; q < 8; q++) {
            int elem = q * 256 + lane * 4;            // float index in wave region
            int nloc = wnb + (elem >> 6);             // local node
            int g = blk * BLK_NODES + nloc;
            if (g < n) {
                float gate01 = gateArr[nloc];
                float4 v = *(const float4*)(fsrc + elem);
                float4 r;
                r.x = v.x + gate01 * tanhf(v.x);
                r.y = v.y + gate01 * tanhf(v.y);
                r.z = v.z + gate01 * tanhf(v.z);
                r.w = v.w + gate01 * tanhf(v.w);
                *(float4*)(fdst + elem) = r;
            }
        }
    }
}

__global__ void finalize_kernel(const float* __restrict__ accf, const int* __restrict__ acci,
                                float* __restrict__ out_scalars) {
    if (threadIdx.x == 0) {
        int c = acci[0];
        float d = (float)(c > 1 ? c : 1);
        out_scalars[0] = accf[0] / d;
        out_scalars[1] = accf[1] / d;
    }
}

extern "C" void kernel_launch(void* const* d_in, const int* in_sizes, int n_in,
                              void* d_out, int out_size, void* d_ws, size_t ws_size,
                              hipStream_t stream) {
    const float* feat  = (const float*)d_in[0];
    const float* radii = (const float*)d_in[1];
    const float* w1rc  = (const float*)d_in[2];
    const float* b1rc  = (const float*)d_in[3];
    const float* w2rc  = (const float*)d_in[4];
    const float* b2rc  = (const float*)d_in[5];
    const float* w3rc  = (const float*)d_in[6];
    const float* b3rc  = (const float*)d_in[7];
    const float* w1cp  = (const float*)d_in[8];
    const float* b1cp  = (const float*)d_in[9];
    const float* w2cp  = (const float*)d_in[10];
    const float* b2cp  = (const float*)d_in[11];
    const int*   eidx  = (const int*)d_in[12];
    const int*   types = (const int*)d_in[13];

    int n = in_sizes[0] / F;          // 300000
    int m = in_sizes[12] / 2;         // 3000000

    // d_ws layout: wt1t (49152 B) | wt2t (12288 B) | pairs (8n) | accf (8) | acci (4)
    short* wt1t = (short*)d_ws;
    short* wt2t = wt1t + 128 * 192;
    unsigned long long* pairs = (unsigned long long*)(wt2t + 48 * 128);
    float* accf = (float*)(pairs + n);
    int*   acci = (int*)(accf + 2);

    float* out         = (float*)d_out;
    float* out_scalars = out + (size_t)n * F;

    unsigned long long sent = ((unsigned long long)(unsigned)n << 32) | (unsigned)n;

    int bs = 256;
    init_kernel<<<(n + bs - 1) / bs, bs, 0, stream>>>(pairs, accf, acci, n, sent);
    prep_w1<<<dim3(128, 3), 64, 0, stream>>>(w1rc, w1cp, wt1t);
    prep_w2<<<dim3(48, 2), 64, 0, stream>>>(w2rc, w2cp, wt2t);
    int mt = (m + 3) / 4;
    edge_pair_kernel<<<(mt + bs - 1) / bs, bs, 0, stream>>>(eidx, eidx + m, pairs, m);
    node_kernel<<<(n + BLK_NODES - 1) / BLK_NODES, bs, 0, stream>>>(
        feat, radii, b1rc, b2rc, w3rc, b3rc, b1cp, b2cp,
        wt1t, wt2t, types, pairs, out, accf, acci, n);
    finalize_kernel<<<1, 64, 0, stream>>>(accf, acci, out_scalars);
}

// Round 6
// 493.724 us; speedup vs baseline: 10.3556x; 1.0001x over previous
//
#include <hip/hip_runtime.h>
#include <math.h>

#define F 64
#define VIOL_THRESH 0.2f
#define BLK_NODES 128
#define H_ROWB 272   // 136 bf16 per row: 68 words ≡ 4 mod 32 banks -> 2-way (free)

typedef float  f32x4  __attribute__((ext_vector_type(4)));
typedef short  bf16x8 __attribute__((ext_vector_type(8)));

__device__ __forceinline__ short f2bf(float f) {
    unsigned u = __builtin_bit_cast(unsigned, f);
    unsigned r = (u + 0x7fffu + ((u >> 16) & 1u)) >> 16;
    return (short)r;
}

__global__ void init_kernel(unsigned long long* __restrict__ pairs,
                            float* __restrict__ accf, int* __restrict__ acci,
                            int n, unsigned long long sent) {
    int i = blockIdx.x * blockDim.x + threadIdx.x;
    if (i < n) pairs[i] = sent;
    if (i == 0) { accf[0] = 0.f; accf[1] = 0.f; acci[0] = 0; }
}

// fp32 features -> bf16 (one-time pass; node kernel then gathers 128B rows)
__global__ void prep_feat(const float* __restrict__ f, short* __restrict__ fb, long total) {
    long t = (long)blockIdx.x * blockDim.x + threadIdx.x;
    long base = t * 8;
    if (base >= total) return;
    float4 a = *(const float4*)(f + base);
    float4 b = *(const float4*)(f + base + 4);
    bf16x8 o;
    o[0] = f2bf(a.x); o[1] = f2bf(a.y); o[2] = f2bf(a.z); o[3] = f2bf(a.w);
    o[4] = f2bf(b.x); o[5] = f2bf(b.y); o[6] = f2bf(b.z); o[7] = f2bf(b.w);
    *(bf16x8*)(fb + base) = o;
}

// wt1t[o][k]: o in [0,128) (64 rc | 64 cp), k in [0,192)
__global__ void prep_w1(const float* __restrict__ w1rc, const float* __restrict__ w1cp,
                        short* __restrict__ wt1t) {
    int o = blockIdx.x;                      // 0..127
    int k = blockIdx.y * 64 + threadIdx.x;   // 0..191
    const float* src = (o < 64) ? (w1rc + o) : (w1cp + (o - 64));
    wt1t[o * 192 + k] = f2bf(src[(size_t)k * 64]);
}

// wt2t[o][k_perm]: 48 x 128 block-diagonal, k permuted to match packed-H layout:
// k_perm = (k&15)*8 + (k>>4)  (dot over k is permutation-invariant)
__global__ void prep_w2(const float* __restrict__ w2rc, const float* __restrict__ w2cp,
                        short* __restrict__ wt2t) {
    int o = blockIdx.x;                      // 0..47
    int k = blockIdx.y * 64 + threadIdx.x;   // 0..127
    float v = 0.f;
    if (o < 32)       { if (k < 64) v = w2rc[k * 32 + o]; }
    else if (o == 32) { if (k >= 64) v = w2cp[k - 64]; }
    int kp = (k & 15) * 8 + (k >> 4);
    wt2t[o * 128 + kp] = f2bf(v);
}

__device__ __forceinline__ void ins2(unsigned long long* __restrict__ p, unsigned v) {
    unsigned long long cur = *p;             // stale-tolerant (monotone decreasing)
    while (true) {
        unsigned m1 = (unsigned)(cur >> 32);
        unsigned m2 = (unsigned)cur;
        unsigned nm1, nm2;
        if (v < m1)                   { nm1 = v;  nm2 = m1; }
        else if (v != m1 && v < m2)   { nm1 = m1; nm2 = v;  }
        else return;
        unsigned long long nw = ((unsigned long long)nm1 << 32) | nm2;
        unsigned long long prev = atomicCAS(p, cur, nw);
        if (prev == cur) return;
        cur = prev;
    }
}

__global__ void edge_pair_kernel(const int* __restrict__ e0, const int* __restrict__ e1,
                                 unsigned long long* __restrict__ pairs, int m) {
    int t = blockIdx.x * blockDim.x + threadIdx.x;
    int base = t * 4;
    if (base >= m) return;
    if (base + 4 <= m) {
        int4 u4 = *(const int4*)(e0 + base);
        int4 v4 = *(const int4*)(e1 + base);
        if (u4.x != v4.x) { ins2(&pairs[u4.x], v4.x); ins2(&pairs[v4.x], u4.x); }
        if (u4.y != v4.y) { ins2(&pairs[u4.y], v4.y); ins2(&pairs[v4.y], u4.y); }
        if (u4.z != v4.z) { ins2(&pairs[u4.z], v4.z); ins2(&pairs[v4.z], u4.z); }
        if (u4.w != v4.w) { ins2(&pairs[u4.w], v4.w); ins2(&pairs[v4.w], u4.w); }
    } else {
        for (int j = base; j < m; j++) {
            int u = e0[j], v = e1[j];
            if (u != v) { ins2(&pairs[u], v); ins2(&pairs[v], u); }
        }
    }
}

template<bool BF>
__global__ __launch_bounds__(256)
void node_kernel(const float* __restrict__ feat, const short* __restrict__ featbf,
                 const float* __restrict__ radii,
                 const float* __restrict__ b1rc, const float* __restrict__ b2rc,
                 const float* __restrict__ w3rc, const float* __restrict__ b3rc,
                 const float* __restrict__ b1cp, const float* __restrict__ b2cp,
                 const short* __restrict__ wt1t, const short* __restrict__ wt2t,
                 const int* __restrict__ types,
                 const unsigned long long* __restrict__ pairs,
                 float* __restrict__ out, float* __restrict__ accf, int* __restrict__ acci,
                 int n) {
    __shared__ __align__(16) char Hbuf[BLK_NODES * H_ROWB];   // 34816 B
    __shared__ float corrArr[BLK_NODES];
    __shared__ float zArr[BLK_NODES];
    __shared__ float gateArr[BLK_NODES];

    int tid = threadIdx.x;
    int blk = blockIdx.x;
    int lane = tid & 63;
    int w = tid >> 6;
    int lm = lane & 15;
    int lg = lane >> 4;
    int wnb = w * 32;

    // node ids per (m-tile, part)
    int nid[2][3];
#pragma unroll
    for (int mt = 0; mt < 2; mt++) {
        int g = blk * BLK_NODES + wnb + mt * 16 + lm;
        int ii = (g < n) ? g : (n - 1);
        unsigned long long pr = pairs[ii];
        int m1 = (int)(pr >> 32);
        int m2 = (int)(unsigned)pr;
        nid[mt][0] = ii;
        nid[mt][1] = (m1 < n) ? m1 : (n - 1);
        nid[mt][2] = (m2 < n) ? m2 : (n - 1);
    }

    // ---------- prefetch ALL layer-1 A-fragments (12 x 16B, all in flight) ----------
    bf16x8 af[2][3][2];
    if constexpr (BF) {
#pragma unroll
        for (int mt = 0; mt < 2; mt++)
#pragma unroll
            for (int part = 0; part < 3; part++)
#pragma unroll
                for (int h = 0; h < 2; h++)
                    af[mt][part][h] = *(const bf16x8*)(featbf + (size_t)nid[mt][part] * F + h * 32 + lg * 8);
    }

    // ---------- layer 1: H[128 nodes][128 outs] ----------
    f32x4 zero4 = {0.f, 0.f, 0.f, 0.f};
    f32x4 acc[2][8];
#pragma unroll
    for (int mt = 0; mt < 2; mt++)
#pragma unroll
        for (int nt = 0; nt < 8; nt++) acc[mt][nt] = zero4;

#pragma unroll
    for (int s = 0; s < 6; s++) {
        int part = s >> 1;
        int h = s & 1;
        bf16x8 a0, a1;
        if constexpr (BF) {
            a0 = af[0][part][h];
            a1 = af[1][part][h];
        } else {
#pragma unroll
            for (int mt = 0; mt < 2; mt++) {
                const float* rp = feat + (size_t)nid[mt][part] * F + h * 32 + lg * 8;
                float4 f0 = *(const float4*)rp;
                float4 f1 = *(const float4*)(rp + 4);
                bf16x8 a;
                a[0] = f2bf(f0.x); a[1] = f2bf(f0.y); a[2] = f2bf(f0.z); a[3] = f2bf(f0.w);
                a[4] = f2bf(f1.x); a[5] = f2bf(f1.y); a[6] = f2bf(f1.z); a[7] = f2bf(f1.w);
                if (mt == 0) a0 = a; else a1 = a;
            }
        }
#pragma unroll
        for (int nt = 0; nt < 8; nt++) {
            bf16x8 b = *(const bf16x8*)(wt1t + (lm + 16 * nt) * 192 + s * 32 + lg * 8);
            acc[0][nt] = __builtin_amdgcn_mfma_f32_16x16x32_bf16(a0, b, acc[0][nt], 0, 0, 0);
            acc[1][nt] = __builtin_amdgcn_mfma_f32_16x16x32_bf16(a1, b, acc[1][nt], 0, 0, 0);
        }
    }

    // biases for this lane's 8 output columns (o = lm + 16*nt)
    float b1v[8];
#pragma unroll
    for (int nt = 0; nt < 8; nt++)
        b1v[nt] = (nt < 4) ? b1rc[lm + 16 * nt] : b1cp[lm + 16 * nt - 64];

    // packed H store: row layout o_perm = lm*8 + nt  -> one ds_write_b128 per (mt,r)
#pragma unroll
    for (int mt = 0; mt < 2; mt++) {
#pragma unroll
        for (int r = 0; r < 4; r++) {
            int node = wnb + mt * 16 + lg * 4 + r;
            bf16x8 hv;
#pragma unroll
            for (int nt = 0; nt < 8; nt++)
                hv[nt] = f2bf(fmaxf(acc[mt][nt][r] + b1v[nt], 0.f));
            *(bf16x8*)(Hbuf + node * H_ROWB + lm * 16) = hv;
        }
    }
    __syncthreads();

    // ---------- layer 2: [128 nodes][33 of 48] (k in permuted order both sides) ----------
    f32x4 acc2[2][3];
#pragma unroll
    for (int mt = 0; mt < 2; mt++)
#pragma unroll
        for (int nt = 0; nt < 3; nt++) acc2[mt][nt] = zero4;

#pragma unroll
    for (int s = 0; s < 4; s++) {
        bf16x8 af2[2];
#pragma unroll
        for (int mt = 0; mt < 2; mt++)
            af2[mt] = *(const bf16x8*)(Hbuf + (wnb + mt * 16 + lm) * H_ROWB + s * 64 + lg * 16);
#pragma unroll
        for (int nt = 0; nt < 3; nt++) {
            bf16x8 b = *(const bf16x8*)(wt2t + (lm + 16 * nt) * 128 + s * 32 + lg * 8);
            acc2[0][nt] = __builtin_amdgcn_mfma_f32_16x16x32_bf16(af2[0], b, acc2[0][nt], 0, 0, 0);
            acc2[1][nt] = __builtin_amdgcn_mfma_f32_16x16x32_bf16(af2[1], b, acc2[1][nt], 0, 0, 0);
        }
    }

    // corr / z per node
#pragma unroll
    for (int mt = 0; mt < 2; mt++) {
#pragma unroll
        for (int r = 0; r < 4; r++) {
            float t = 0.f;
#pragma unroll
            for (int nt = 0; nt < 2; nt++) {
                int o = lm + 16 * nt;
                float s2v = fmaxf(acc2[mt][nt][r] + b2rc[o], 0.f);
                t = fmaf(s2v, w3rc[o], t);
            }
            float zz = acc2[mt][2][r];   // only o==32 (lm==0) nonzero; rest exact zeros
#pragma unroll
            for (int msk = 1; msk < 16; msk <<= 1) {
                t  += __shfl_xor(t, msk);
                zz += __shfl_xor(zz, msk);
            }
            if (lm == 0) {
                int node = wnb + mt * 16 + lg * 4 + r;
                corrArr[node] = t + b3rc[0];
                zArr[node]    = zz + b2cp[0];
            }
        }
    }
    __syncthreads();

    // ---------- epilogue: viol / gate / averages ----------
    float sv = 0.f, sc = 0.f; int ct = 0;
    if (tid < BLK_NODES) {
        int g = blk * BLK_NODES + tid;
        bool live = g < n;
        int ii = live ? g : (n - 1);
        unsigned long long pr = pairs[ii];
        int m1 = (int)(pr >> 32);
        int m2 = (int)(unsigned)pr;
        bool valid = m2 < n;
        int c1 = (m1 < n) ? m1 : (n - 1);
        int c2 = (m2 < n) ? m2 : (n - 1);
        float rp_ = radii[ii], r1_ = radii[c1], r2_ = radii[c2];
        float pr3 = rp_ * rp_ * rp_;
        float viol = fabsf(r1_ * r1_ * r1_ + r2_ * r2_ * r2_ - pr3) / pr3;
        bool active = live && valid && (types[ii] == 1);
        bool upd = active && (viol > VIOL_THRESH);
        float gate = upd ? corrArr[tid] : 0.f;
        gateArr[tid] = 0.1f * gate;
        if (active) {
            sv = viol;
            sc = 1.0f / (1.0f + expf(-zArr[tid]));
            ct = 1;
        }
    }
#pragma unroll
    for (int off = 32; off > 0; off >>= 1) {
        sv += __shfl_down(sv, off);
        sc += __shfl_down(sc, off);
        ct += __shfl_down(ct, off);
    }
    if (lane == 0 && (sv != 0.f || sc != 0.f || ct != 0)) {
        atomicAdd(&accf[0], sv);
        atomicAdd(&accf[1], sc);
        atomicAdd(acci, ct);
    }
    __syncthreads();

    // ---------- coalesced feature update ----------
    {
        size_t wbase = (size_t)(blk * BLK_NODES + wnb) * F;
        const float* fsrc = feat + wbase;
        float* fdst = out + wbase;
#pragma unroll
        for (int q = 0; q < 8; q++) {
            int elem = q * 256 + lane * 4;
            int nloc = wnb + (elem >> 6);
            int g = blk * BLK_NODES + nloc;
            if (g < n) {
                float gate01 = gateArr[nloc];
                float4 v = *(const float4*)(fsrc + elem);
                float4 r;
                r.x = v.x + gate01 * tanhf(v.x);
                r.y = v.y + gate01 * tanhf(v.y);
                r.z = v.z + gate01 * tanhf(v.z);
                r.w = v.w + gate01 * tanhf(v.w);
                *(float4*)(fdst + elem) = r;
            }
        }
    }
}

__global__ void finalize_kernel(const float* __restrict__ accf, const int* __restrict__ acci,
                                float* __restrict__ out_scalars) {
    if (threadIdx.x == 0) {
        int c = acci[0];
        float d = (float)(c > 1 ? c : 1);
        out_scalars[0] = accf[0] / d;
        out_scalars[1] = accf[1] / d;
    }
}

extern "C" void kernel_launch(void* const* d_in, const int* in_sizes, int n_in,
                              void* d_out, int out_size, void* d_ws, size_t ws_size,
                              hipStream_t stream) {
    const float* feat  = (const float*)d_in[0];
    const float* radii = (const float*)d_in[1];
    const float* w1rc  = (const float*)d_in[2];
    const float* b1rc  = (const float*)d_in[3];
    const float* w2rc  = (const float*)d_in[4];
    const float* b2rc  = (const float*)d_in[5];
    const float* w3rc  = (const float*)d_in[6];
    const float* b3rc  = (const float*)d_in[7];
    const float* w1cp  = (const float*)d_in[8];
    const float* b1cp  = (const float*)d_in[9];
    const float* w2cp  = (const float*)d_in[10];
    const float* b2cp  = (const float*)d_in[11];
    const int*   eidx  = (const int*)d_in[12];
    const int*   types = (const int*)d_in[13];

    int n = in_sizes[0] / F;          // 300000
    int m = in_sizes[12] / 2;         // 3000000

    // ws layout: wt1t | wt2t | pairs | accf | acci | pad | featbf
    char* ws = (char*)d_ws;
    short* wt1t = (short*)ws;                         ws += 128 * 192 * 2;
    short* wt2t = (short*)ws;                         ws += 48 * 128 * 2;
    unsigned long long* pairs = (unsigned long long*)ws; ws += (size_t)n * 8;
    float* accf = (float*)ws;                         ws += 8;
    int*   acci = (int*)ws;                           ws += 8;   // keep 16B align
    short* featbf = (short*)ws;
    size_t featbf_bytes = (size_t)n * F * 2;
    bool useBF = ((size_t)(ws - (char*)d_ws) + featbf_bytes) <= ws_size;

    float* out         = (float*)d_out;
    float* out_scalars = out + (size_t)n * F;

    unsigned long long sent = ((unsigned long long)(unsigned)n << 32) | (unsigned)n;

    int bs = 256;
    init_kernel<<<(n + bs - 1) / bs, bs, 0, stream>>>(pairs, accf, acci, n, sent);
    prep_w1<<<dim3(128, 3), 64, 0, stream>>>(w1rc, w1cp, wt1t);
    prep_w2<<<dim3(48, 2), 64, 0, stream>>>(w2rc, w2cp, wt2t);
    if (useBF) {
        long total = (long)n * F;
        long nthr = total / 8;
        prep_feat<<<(unsigned)((nthr + bs - 1) / bs), bs, 0, stream>>>(feat, featbf, total);
    }
    int mt = (m + 3) / 4;
    edge_pair_kernel<<<(mt + bs - 1) / bs, bs, 0, stream>>>(eidx, eidx + m, pairs, m);
    int nblocks = (n + BLK_NODES - 1) / BLK_NODES;
    if (useBF) {
        node_kernel<true><<<nblocks, bs, 0, stream>>>(
            feat, featbf, radii, b1rc, b2rc, w3rc, b3rc, b1cp, b2cp,
            wt1t, wt2t, types, pairs, out, accf, acci, n);
    } else {
        node_kernel<false><<<nblocks, bs, 0, stream>>>(
            feat, featbf, radii, b1rc, b2rc, w3rc, b3rc, b1cp, b2cp,
            wt1t, wt2t, types, pairs, out, accf, acci, n);
    }
    finalize_kernel<<<1, 64, 0, stream>>>(accf, acci, out_scalars);
}